// Round 7
// baseline (525.962 us; speedup 1.0000x reference)
//
#include <hip/hip_runtime.h>

typedef unsigned int u32;
typedef unsigned short u16;
typedef __attribute__((ext_vector_type(8))) short bf16x8;   // 8 bf16 in 4 VGPRs
typedef __attribute__((ext_vector_type(4))) float f32x4;

#define GLOBAL_AS __attribute__((address_space(1)))
#define LDS_AS    __attribute__((address_space(3)))

#define B_   64
#define T_   256
#define E_   1024
#define H_   16
#define HD_  64
#define NTOK (B_*T_)          // 16384
#define K_   1024
#define LNEPS 1e-5f

// ---------- bf16 helpers ----------
__device__ __forceinline__ u16 f2bf(float f){            // round-to-nearest-even
  u32 x = __float_as_uint(f);
  u32 r = x + 0x7fffu + ((x >> 16) & 1u);
  return (u16)(r >> 16);
}
__device__ __forceinline__ u16 f2bf_trunc(float f){      // truncate (P probs only)
  return (u16)(__float_as_uint(f) >> 16);
}
__device__ __forceinline__ u32 pack2(float a, float b){
  return (u32)f2bf(a) | ((u32)f2bf(b) << 16);
}

// async global->LDS, 16 B per lane (dest = wave-uniform base + lane*16)
__device__ __forceinline__ void gload16(const u16* g, u16* l){
  __builtin_amdgcn_global_load_lds((const GLOBAL_AS void*)g, (LDS_AS void*)l, 16, 0, 0);
}

// ---------- fused LayerNorm fp32 -> bf16, one wave per token ----------
__global__ __launch_bounds__(256) void ln_bf16_kernel(
    const float* __restrict__ x, const float* __restrict__ g,
    const float* __restrict__ b, u16* __restrict__ o)
{
  int lane  = threadIdx.x & 63;
  int token = (blockIdx.x << 2) + (threadIdx.x >> 6);
  const float4* xr = (const float4*)(x + (size_t)token * E_);
  float4 v[4];
  float s = 0.f, ss = 0.f;
  #pragma unroll
  for (int i = 0; i < 4; ++i){
    v[i] = xr[lane + 64 * i];
    s += v[i].x + v[i].y + v[i].z + v[i].w;
    ss = fmaf(v[i].x, v[i].x, fmaf(v[i].y, v[i].y,
         fmaf(v[i].z, v[i].z, fmaf(v[i].w, v[i].w, ss))));
  }
  #pragma unroll
  for (int off = 32; off > 0; off >>= 1){
    s  += __shfl_xor(s,  off);
    ss += __shfl_xor(ss, off);
  }
  float mu   = s * (1.f / E_);
  float var  = ss * (1.f / E_) - mu * mu;
  float rstd = rsqrtf(var + LNEPS);
  const float4* gr = (const float4*)g;
  const float4* br = (const float4*)b;
  uint2* orow = (uint2*)(o + (size_t)token * E_);
  #pragma unroll
  for (int i = 0; i < 4; ++i){
    float4 gg = gr[lane + 64 * i], bb = br[lane + 64 * i];
    float y0 = (v[i].x - mu) * rstd * gg.x + bb.x;
    float y1 = (v[i].y - mu) * rstd * gg.y + bb.y;
    float y2 = (v[i].z - mu) * rstd * gg.z + bb.z;
    float y3 = (v[i].w - mu) * rstd * gg.w + bb.w;
    orow[lane + 64 * i] = make_uint2(pack2(y0, y1), pack2(y2, y3));
  }
}

// ---------- weight prep: fragment-major B layout ----------
// elem(n, k) at o16 = (nb*32 + s)*2048 + j*512 + (quad*16 + l15)*8 + e
// where n = nb*64 + j*16 + l15, k = s*32 + quad*8 + e.
__global__ __launch_bounds__(256) void convq_kernel(
    const float* __restrict__ wk, const float* __restrict__ wq,
    const float* __restrict__ wv, u16* __restrict__ o)
{
  __shared__ float tile[64 * 68];            // [k-local][d], +4 pad
  const int zh = blockIdx.x, z = zh >> 4, h = zh & 15;
  const int k0 = blockIdx.y << 6;
  const float* w = (z == 0 ? wk : z == 1 ? wq : wv) + (size_t)h * (E_ * HD_);
  const int t = threadIdx.x;
  {
    int kr = t >> 2, d0 = (t & 3) << 4;
    const float4* src = (const float4*)(w + (size_t)(k0 + kr) * HD_ + d0);
    #pragma unroll
    for (int i = 0; i < 4; ++i)
      *(float4*)(tile + kr * 68 + d0 + 4 * i) = src[i];
  }
  __syncthreads();
  {
    const size_t nb32 = (size_t)zh * 32 + (k0 >> 5);   // nb == zh
    #pragma unroll
    for (int u = 0; u < 2; ++u) {
      int cid = t * 2 + u;
      int dd = cid >> 3, kc = cid & 7;
      u32 wd[4];
      #pragma unroll
      for (int e2 = 0; e2 < 4; ++e2)
        wd[e2] = pack2(tile[(kc * 8 + 2 * e2) * 68 + dd],
                       tile[(kc * 8 + 2 * e2 + 1) * 68 + dd]);
      u16* dst = o + (nb32 + (kc >> 2)) * 2048 + (size_t)(dd >> 4) * 512
                   + (size_t)(((kc & 3) << 4) + (dd & 15)) * 8;
      *(uint4*)dst = make_uint4(wd[0], wd[1], wd[2], wd[3]);
    }
  }
}

// w [E][E] fp32, B(n,k) = w[k][n] -> fragment-major bf16; z selects {proj,w1,w2}
__global__ __launch_bounds__(256) void convt3_kernel(
    const float* __restrict__ wp, const float* __restrict__ w1,
    const float* __restrict__ w2, u16* __restrict__ op,
    u16* __restrict__ o1, u16* __restrict__ o2)
{
  __shared__ float tile[64 * 68];            // [k-local][n-local]
  const int z = blockIdx.z;
  const float* w = (z == 0 ? wp : z == 1 ? w1 : w2);
  u16* o = (z == 0 ? op : z == 1 ? o1 : o2);
  const int n0 = blockIdx.x << 6, k0 = blockIdx.y << 6;
  const int t = threadIdx.x;
  {
    int kr = t >> 2, nn = (t & 3) << 4;
    const float4* src = (const float4*)(w + (size_t)(k0 + kr) * E_ + n0 + nn);
    #pragma unroll
    for (int i = 0; i < 4; ++i)
      *(float4*)(tile + kr * 68 + nn + 4 * i) = src[i];
  }
  __syncthreads();
  {
    const size_t nb32 = (size_t)(n0 >> 6) * 32 + (k0 >> 5);
    #pragma unroll
    for (int u = 0; u < 2; ++u) {
      int cid = t * 2 + u;
      int dd = cid >> 3, kc = cid & 7;
      u32 wd[4];
      #pragma unroll
      for (int e2 = 0; e2 < 4; ++e2)
        wd[e2] = pack2(tile[(kc * 8 + 2 * e2) * 68 + dd],
                       tile[(kc * 8 + 2 * e2 + 1) * 68 + dd]);
      u16* dst = o + (nb32 + (kc >> 2)) * 2048 + (size_t)(dd >> 4) * 512
                   + (size_t)(((kc & 3) << 4) + (dd & 15)) * 8;
      *(uint4*)dst = make_uint4(wd[0], wd[1], wd[2], wd[3]);
    }
  }
}

// ---------- MFMA GEMM: C(M x N) = A(M x 1024) * B^T, B fragment-major ----------
// 128x128 tile / 256 threads (4 waves 2M x 2N), per-wave 64x64 (acc[4][4]).
// A-only LDS 4-slot ring (BK=32, 8 KB slices) = 32 KB; 3 blocks/CU (Occ 30%).
// M-INNER intra-XCD walk: A panel L2-hot, B n-tile read by 16 near-simultaneous
// blocks (round 6: FETCH 272->148 MB vs n-inner).
// Pipeline per slice: phase A issues ds_reads for row-half 1 + stages A(s+3),
// MFMAs row-half 0; phase B issues next slice's row-half-0 reads, MFMAs row-
// half 1; B-fragments (global, L2-resident weights) loaded 2 slices ahead.
// One barrier/slice; vmcnt counted (10/8/4), never 0 mid-loop.
// MODE 0: qkv -> k,q bf16 (b,h,t,d); v bf16 TRANSPOSED (b,h,d,t)
// MODE 1: proj -> Cf fp32 = acc + bias + resid              [row-major]
// MODE 2: ff1  -> Cb bf16 = relu(acc + bias)
// MODE 3: ff2  -> Cf fp32 = acc + bias + Cf (in-place residual)
#define MF4(I, AV, BV)                                                               \
  acc[I][0] = __builtin_amdgcn_mfma_f32_16x16x32_bf16(AV, BV[0], acc[I][0], 0, 0, 0);\
  acc[I][1] = __builtin_amdgcn_mfma_f32_16x16x32_bf16(AV, BV[1], acc[I][1], 0, 0, 0);\
  acc[I][2] = __builtin_amdgcn_mfma_f32_16x16x32_bf16(AV, BV[2], acc[I][2], 0, 0, 0);\
  acc[I][3] = __builtin_amdgcn_mfma_f32_16x16x32_bf16(AV, BV[3], acc[I][3], 0, 0, 0);

#define BLOADS(BV, SS) {                                                      \
    const u16* bp_ = Bp + (size_t)(SS) * 2048;                                \
    BV[0] = *(const bf16x8*)(bp_);                                            \
    BV[1] = *(const bf16x8*)(bp_ + 512);                                      \
    BV[2] = *(const bf16x8*)(bp_ + 1024);                                     \
    BV[3] = *(const bf16x8*)(bp_ + 1536);                                     \
  }

// SLOT: ring slot of slice s. NSLOT: slot of slice s+1 (phase-B lookahead read).
// ACUR: row-half-0 regs of slice s (read in previous slice's phase B).
// ATMP: row-half-1 regs (read phase A).  ANXT: next slice's row-half 0.
#define MSLICE2(SLOT, NSLOT, KA, DO_STAGE, DO_NXT, DO_BL, BS, ACUR, ATMP, ANXT, BV, BNV, VM) { \
    const u16* As_ = lds + (SLOT) * 4096;                                     \
    /* phase A: issue row-half-1 reads, stage A(s+3), MFMA row-half 0 */      \
    ATMP[0] = *(const bf16x8*)(As_ + aoffb + 1024);                           \
    ATMP[1] = *(const bf16x8*)(As_ + aoffb + 1536);                           \
    if (DO_STAGE) {                                                           \
      u16* d_ = lds + (((SLOT) + 3) & 3) * 4096;                              \
      gload16(Ag0 + (KA), d_ + tid * 8);                                      \
      gload16(Ag1 + (KA), d_ + 2048 + tid * 8);                               \
    }                                                                         \
    __builtin_amdgcn_s_setprio(1);                                            \
    MF4(0, ACUR[0], BV) MF4(1, ACUR[1], BV)                                   \
    __builtin_amdgcn_s_setprio(0);                                            \
    /* phase B: issue next slice row-half-0 reads, MFMA row-half 1 */         \
    if (DO_NXT) {                                                             \
      const u16* An_ = lds + (NSLOT) * 4096;                                  \
      ANXT[0] = *(const bf16x8*)(An_ + aoffb);                                \
      ANXT[1] = *(const bf16x8*)(An_ + aoffb + 512);                          \
    }                                                                         \
    __builtin_amdgcn_s_setprio(1);                                            \
    MF4(2, ATMP[0], BV) MF4(3, ATMP[1], BV)                                   \
    __builtin_amdgcn_s_setprio(0);                                            \
    if (DO_BL) { BLOADS(BNV, BS) }                                            \
    VM;                                                                       \
    __builtin_amdgcn_s_barrier();                                             \
    __builtin_amdgcn_sched_barrier(0);                                        \
    asm volatile("" ::: "memory");                                            \
  }

#define VM10 asm volatile("s_waitcnt vmcnt(10)" ::: "memory")
#define VM8  asm volatile("s_waitcnt vmcnt(8)"  ::: "memory")
#define VM4  asm volatile("s_waitcnt vmcnt(4)"  ::: "memory")

template<int MODE>
__global__ __launch_bounds__(256, 3) void mgemm_kernel(
    const u16* __restrict__ A, const u16* __restrict__ Bt,
    const float* __restrict__ bias, const float* __restrict__ resid,
    float* __restrict__ Cf, u16* __restrict__ Cb, u16* __restrict__ Cb2)
{
  __shared__ __align__(16) u16 lds[16384];   // 32 KB: A-ring, epilogue reuse

  const int tid = threadIdx.x, lane = tid & 63, wid = tid >> 6;
  const int wm = wid >> 1, wn = wid & 1;
  const int l15 = lane & 15, quad = lane >> 4;

  // XCD-aware mapping, M-INNER intra-XCD walk (see header comment).
  const int b = (int)blockIdx.x;
  const int xcd = b & 7, ib = b >> 3;
  const int mloc = ib & 15, ntile = ib >> 4;
  const int row0 = (xcd * 16 + mloc) << 7;
  const int col0 = ntile << 7;

  // A staging: pre-swizzled global source, lane-linear LDS dest.
  const int sc   = (tid & 7) ^ ((tid >> 3) & 7);
  const int srow = 2 * (tid >> 3) + (sc >> 2);          // 0..63
  const int skof = (sc & 3) << 3;
  const u16* Ag0 = A + (size_t)(row0 + srow) * K_ + skof;
  const u16* Ag1 = Ag0 + (size_t)64 * K_;

  // A fragment read offsets (paired-row + 3-bit XOR; consecutive-8-lane
  // batches of a ds_read_b128 cover all 8 bank groups)
  const int rhalf = l15 >> 1;
  const int cph   = ((((l15 & 1) << 2) | quad) ^ rhalf);
  const int aoffb = wm * 2048 + rhalf * 64 + cph * 8;

  // B fragment-major pointer: nb = col0/64 + wn
  const u16* Bp = Bt + (size_t)((col0 >> 6) + wn) * 65536 + lane * 8;

  f32x4 acc[4][4];
  #pragma unroll
  for (int i = 0; i < 4; ++i)
    #pragma unroll
    for (int j = 0; j < 4; ++j)
      acc[i][j] = (f32x4){0.f, 0.f, 0.f, 0.f};

  bf16x8 aA[2], aB[2], aT[2], bE[4], bO[4];

  // prologue: A slices 0..2 (6 loads) + B(0),B(1) (8 loads); VM10 confirms
  // slots 0 AND 1 staged (slice 0 phase B reads slot 1).
  #pragma unroll
  for (int t3 = 0; t3 < 3; ++t3) {
    u16* d_ = lds + t3 * 4096;
    gload16(Ag0 + t3 * 32, d_ + tid * 8);
    gload16(Ag1 + t3 * 32, d_ + 2048 + tid * 8);
  }
  BLOADS(bE, 0)
  BLOADS(bO, 1)
  asm volatile("s_waitcnt vmcnt(10)" ::: "memory");
  __builtin_amdgcn_s_barrier();
  __builtin_amdgcn_sched_barrier(0);
  asm volatile("" ::: "memory");

  // slice 0's row-half-0 regs
  aA[0] = *(const bf16x8*)(lds + aoffb);
  aA[1] = *(const bf16x8*)(lds + aoffb + 512);

  // main: 32 slices of K=32; stage A(s+3), load B(s+2).
  #pragma unroll 1
  for (int s = 0; s < 28; s += 2) {
    MSLICE2(s & 3, (s + 1) & 3, (s + 3) * 32, 1, 1, 1, s + 2, aA, aT, aB, bE, bE, VM10)
    MSLICE2((s + 1) & 3, (s + 2) & 3, (s + 4) * 32, 1, 1, 1, s + 3, aB, aT, aA, bO, bO, VM10)
  }
  MSLICE2(0, 1, 31 * 32, 1, 1, 1, 30, aA, aT, aB, bE, bE, VM10)   // s=28
  MSLICE2(1, 2, 0,       0, 1, 1, 31, aB, aT, aA, bO, bO, VM8 )   // s=29
  MSLICE2(2, 3, 0,       0, 1, 0, 0,  aA, aT, aB, bE, bE, VM4 )   // s=30
  MSLICE2(3, 0, 0,       0, 0, 0, 0,  aB, aT, aA, bO, bO, (void)0)// s=31

  if (MODE == 1 || MODE == 3) {
    // fp32 row-major epilogue (dword-coalesced scalar stores)
    const int rbase = row0 + wm * 64;
    #pragma unroll
    for (int j = 0; j < 4; ++j) {
      const int n = col0 + wn * 64 + j * 16 + l15;
      const float bn = bias[n];
      #pragma unroll
      for (int i = 0; i < 4; ++i)
        #pragma unroll
        for (int r = 0; r < 4; ++r) {
          const int row = rbase + i * 16 + quad * 4 + r;
          const size_t idx = (size_t)row * E_ + n;
          float v = acc[i][j][r] + bn;
          if (MODE == 1) Cf[idx] = v + resid[idx];
          else           Cf[idx] = v + Cf[idx];
        }
    }
    return;
  }

  // ---- bf16 epilogues via per-wave 8-KB LDS transpose -> 16-B coalesced stores ----
  // (wave-private buffers; same-wave DS ordering makes barriers unnecessary)
  u16* ep = lds + wid * 4096;                  // 64x64 u16, row stride 64
  const int nb0 = col0 + wn * 64;              // wave's 64-col window (64-aligned)

  if (MODE == 2) {
    #pragma unroll
    for (int j = 0; j < 4; ++j) {
      const float bn = bias[nb0 + j * 16 + l15];
      #pragma unroll
      for (int i = 0; i < 4; ++i)
        #pragma unroll
        for (int r = 0; r < 4; ++r)
          ep[(i*16 + quad*4 + r) * 64 + j*16 + l15] =
              f2bf(fmaxf(acc[i][j][r] + bn, 0.f));
    }
    const int rbase = row0 + wm * 64;
    #pragma unroll
    for (int it = 0; it < 8; ++it) {
      const int tl = it * 8 + (lane >> 3), c = lane & 7;
      uint4 v = *(const uint4*)(ep + tl * 64 + c * 8);
      *(uint4*)(Cb + (size_t)(rbase + tl) * E_ + nb0 + c * 8) = v;
    }
    return;
  }

  // MODE 0: z = 0 (k), 1 (q): row-major (b,h,t,d). z = 2 (v): transposed (b,h,d,t).
  const int z = nb0 >> 10, hh = (nb0 >> 6) & 15;
  const int rows0 = row0 + wm * 64;
  const int bb = rows0 >> 8, tb = rows0 & 255;
  if (z < 2) {
    #pragma unroll
    for (int i = 0; i < 4; ++i)
      #pragma unroll
      for (int j = 0; j < 4; ++j)
        #pragma unroll
        for (int r = 0; r < 4; ++r)
          ep[(i*16 + quad*4 + r) * 64 + j*16 + l15] = f2bf(acc[i][j][r]);
    u16* out = (z == 0 ? Cb : Cb2) + ((size_t)(bb * H_ + hh) * T_ + tb) * HD_;
    #pragma unroll
    for (int it = 0; it < 8; ++it) {
      const int tl = it * 8 + (lane >> 3), c = lane & 7;
      uint4 v = *(const uint4*)(ep + tl * 64 + c * 8);
      *(uint4*)(out + (size_t)tl * HD_ + c * 8) = v;
    }
  } else {
    // write transposed [d][t'], 8x16B chunks swizzled: phys = (t'>>3) ^ (d&7)
    #pragma unroll
    for (int i = 0; i < 4; ++i)
      #pragma unroll
      for (int j = 0; j < 4; ++j)
        #pragma unroll
        for (int r = 0; r < 4; ++r) {
          const int tl = i*16 + quad*4 + r, d = j*16 + l15;
          const int cs = (tl >> 3) ^ (d & 7);
          ep[d * 64 + cs * 8 + (tl & 7)] = f2bf(acc[i][j][r]);
        }
    u16* out = (u16*)Cf + ((size_t)(bb * H_ + hh) * HD_) * T_;
    #pragma unroll
    for (int it = 0; it < 8; ++it) {
      const int d = it * 8 + (lane >> 3), c = lane & 7;
      const int cs = c ^ (d & 7);
      uint4 v = *(const uint4*)(ep + d * 64 + cs * 8);
      *(uint4*)(out + (size_t)d * T_ + tb + c * 8) = v;
    }
  }
}

// ---------- MFMA flash attention: block = one bh, wave = one t-block ----------
// scores[t][s] = k_t . q_s / 8 (K.Q^T per reference), causal s<=t.
// k,q bf16 (b,h,t,d); vt bf16 (b,h,d,t); out bf16 row-major (b,t,h*64+d).
// BALANCED: tblk = wv -> every block does exactly 1+2+3+4 = 10 KV-iterations.
// No barriers (Pb per-wave private); divergent trip counts are safe.
// ILP: qf held persistently, Q(sb+1) issued right after the QK MFMAs (anti-dep
// ordering); all V(sb) loads issued before the softmax -- both land under
// ~800 cy of softmax VALU.  launch_bounds(256,1): regs may exceed 256 without
// spill (occupancy is 1 wave/SIMD regardless -- acc state alone caps it).
__global__ __launch_bounds__(256, 1) void fattn_kernel(
    const u16* __restrict__ kk_, const u16* __restrict__ qq_,
    const u16* __restrict__ vt_, u16* __restrict__ out)
{
  __shared__ __align__(16) u16 Pb[4][64 * 72];  // per-wave private, 9216 B each
  const int tid = threadIdx.x, lane = tid & 63, wv = tid >> 6;
  const int bh = blockIdx.x;
  const int tblk = wv;
  const int l15 = lane & 15, quad = lane >> 4;
  const u16* kb  = kk_ + (size_t)bh * (T_ * HD_);
  const u16* qb  = qq_ + (size_t)bh * (T_ * HD_);
  const u16* vtb = vt_ + (size_t)bh * (HD_ * T_);
  u16* Pw = Pb[wv];

  bf16x8 kf[4][2];
  #pragma unroll
  for (int i = 0; i < 4; ++i)
    #pragma unroll
    for (int c = 0; c < 2; ++c)
      kf[i][c] = *(const bf16x8*)(kb + (size_t)(tblk*64 + i*16 + l15) * HD_ + c*32 + quad*8);

  // Q(0) preload (persistent fragment buffer)
  bf16x8 qf[4][2];
  #pragma unroll
  for (int j = 0; j < 4; ++j)
    #pragma unroll
    for (int c = 0; c < 2; ++c)
      qf[j][c] = *(const bf16x8*)(qb + (size_t)(j*16 + l15) * HD_ + c*32 + quad*8);

  f32x4 o[4][4];
  float mrow[4][4], lrow[4][4];
  #pragma unroll
  for (int i = 0; i < 4; ++i) {
    #pragma unroll
    for (int j = 0; j < 4; ++j) o[i][j] = (f32x4){0.f, 0.f, 0.f, 0.f};
    #pragma unroll
    for (int r = 0; r < 4; ++r) { mrow[i][r] = -1e30f; lrow[i][r] = 0.f; }
  }

  for (int sb = 0; sb <= tblk; ++sb) {
    // ---- QK^T on current qf ----
    f32x4 S[4][4];
    __builtin_amdgcn_s_setprio(1);
    #pragma unroll
    for (int j = 0; j < 4; ++j)
      #pragma unroll
      for (int i = 0; i < 4; ++i) {
        f32x4 t0 = __builtin_amdgcn_mfma_f32_16x16x32_bf16(kf[i][0], qf[j][0],
                       (f32x4){0.f,0.f,0.f,0.f}, 0, 0, 0);
        S[i][j] = __builtin_amdgcn_mfma_f32_16x16x32_bf16(kf[i][1], qf[j][1], t0, 0, 0, 0);
      }
    __builtin_amdgcn_s_setprio(0);
    // ---- prefetch Q(sb+1): anti-dependency on qf orders these after the MFMAs ----
    if (sb < tblk) {
      #pragma unroll
      for (int j = 0; j < 4; ++j)
        #pragma unroll
        for (int c = 0; c < 2; ++c)
          qf[j][c] = *(const bf16x8*)(qb + (size_t)((sb+1)*64 + j*16 + l15) * HD_ + c*32 + quad*8);
    }
    // ---- V(sb) loads: consumed after P round-trip, latency hidden by softmax ----
    bf16x8 vf[4][2];
    #pragma unroll
    for (int jd = 0; jd < 4; ++jd)
      #pragma unroll
      for (int c = 0; c < 2; ++c)
        vf[jd][c] = *(const bf16x8*)(vtb + (size_t)(jd*16 + l15) * T_ + sb*64 + c*32 + quad*8);
    // ---- scale + causal mask ----
    #pragma unroll
    for (int i = 0; i < 4; ++i)
      #pragma unroll
      for (int j = 0; j < 4; ++j)
        #pragma unroll
        for (int r = 0; r < 4; ++r) {
          float val = S[i][j][r] * 0.125f;
          if (sb == tblk) {
            int tl = i*16 + quad*4 + r, sl = j*16 + l15;
            if (sl > tl) val = -1e30f;
          }
          S[i][j][r] = val;
        }
    // ---- online softmax ----
    #pragma unroll
    for (int i = 0; i < 4; ++i)
      #pragma unroll
      for (int r = 0; r < 4; ++r) {
        float mx = fmaxf(fmaxf(S[i][0][r], S[i][1][r]), fmaxf(S[i][2][r], S[i][3][r]));
        #pragma unroll
        for (int msk = 1; msk < 16; msk <<= 1) mx = fmaxf(mx, __shfl_xor(mx, msk));
        float mn = fmaxf(mrow[i][r], mx);
        float al = __expf(mrow[i][r] - mn);
        mrow[i][r] = mn;
        float sm = 0.f;
        #pragma unroll
        for (int j = 0; j < 4; ++j) {
          float p = __expf(S[i][j][r] - mn);
          S[i][j][r] = p;
          sm += p;
        }
        #pragma unroll
        for (int msk = 1; msk < 16; msk <<= 1) sm += __shfl_xor(sm, msk);
        lrow[i][r] = lrow[i][r] * al + sm;
        #pragma unroll
        for (int jd = 0; jd < 4; ++jd) o[i][jd][r] *= al;
      }
    // ---- P -> private LDS, fragment reads ----
    #pragma unroll
    for (int i = 0; i < 4; ++i)
      #pragma unroll
      for (int j = 0; j < 4; ++j)
        #pragma unroll
        for (int r = 0; r < 4; ++r)
          Pw[(i*16 + quad*4 + r) * 72 + j*16 + l15] = f2bf_trunc(S[i][j][r]);
    bf16x8 pf[4][2];
    #pragma unroll
    for (int i = 0; i < 4; ++i)
      #pragma unroll
      for (int c = 0; c < 2; ++c)
        pf[i][c] = *(const bf16x8*)(Pw + (i*16 + l15) * 72 + c*32 + quad*8);
    // ---- O += P . V ----
    __builtin_amdgcn_s_setprio(1);
    #pragma unroll
    for (int jd = 0; jd < 4; ++jd)
      #pragma unroll
      for (int i = 0; i < 4; ++i) {
        f32x4 t0 = __builtin_amdgcn_mfma_f32_16x16x32_bf16(pf[i][0], vf[jd][0], o[i][jd], 0, 0, 0);
        o[i][jd] = __builtin_amdgcn_mfma_f32_16x16x32_bf16(pf[i][1], vf[jd][1], t0, 0, 0, 0);
      }
    __builtin_amdgcn_s_setprio(0);
  }

  // ---- normalize, transpose via private LDS, coalesced store ----
  #pragma unroll
  for (int i = 0; i < 4; ++i)
    #pragma unroll
    for (int r = 0; r < 4; ++r) {
      float inv = 1.0f / lrow[i][r];
      #pragma unroll
      for (int jd = 0; jd < 4; ++jd)
        Pw[(i*16 + quad*4 + r) * 72 + jd*16 + l15] = f2bf(o[i][jd][r] * inv);
    }
  {
    const int b = bh >> 4, h = bh & 15;
    const uint4* pr = (const uint4*)(Pw + lane * 72);
    uint4* og = (uint4*)(out + ((size_t)(b * T_ + tblk*64 + lane)) * E_ + h * HD_);
    #pragma unroll
    for (int k = 0; k < 8; ++k) og[k] = pr[k];
  }
}

// ---------- launch ----------
extern "C" void kernel_launch(void* const* d_in, const int* in_sizes, int n_in,
                              void* d_out, int out_size, void* d_ws, size_t ws_size,
                              hipStream_t stream) {
  const float* x     = (const float*)d_in[0];
  const float* ln1g  = (const float*)d_in[1];
  const float* ln1b  = (const float*)d_in[2];
  const float* wk    = (const float*)d_in[3];
  const float* wq    = (const float*)d_in[4];
  const float* wv    = (const float*)d_in[5];
  const float* wproj = (const float*)d_in[6];
  const float* bproj = (const float*)d_in[7];
  const float* ln2g  = (const float*)d_in[8];
  const float* ln2b  = (const float*)d_in[9];
  const float* w1    = (const float*)d_in[10];
  const float* b1    = (const float*)d_in[11];
  const float* w2    = (const float*)d_in[12];
  const float* b2    = (const float*)d_in[13];
  float* outp = (float*)d_out;

  // ws (112 MB <= proven 128 MB):
  //  [0,6M) WqkvF | [6,8M) WprojF | [8,10M) W1F | [10,12M) W2F   (fragment-major)
  //  [16,48M) hb bf16 (LN1 out -> attn out)
  //  [48,80M) k bf16 (bhtd) -> h2 bf16 | [80,112M) q bf16 (bhtd) -> ff1 bf16
  // d_out (64MB): v^T bf16 (b,h,d,t) [0,32M) -> x1 fp32 (full) -> out (in-place)
  char* ws = (char*)d_ws;
  const size_t MB = 1024 * 1024;
  u16* wqkvT  = (u16*)(ws);
  u16* wprojT = (u16*)(ws + 6 * MB);
  u16* w1T    = (u16*)(ws + 8 * MB);
  u16* w2T    = (u16*)(ws + 10 * MB);
  u16* hb     = (u16*)(ws + 16 * MB);
  u16* kbuf   = (u16*)(ws + 48 * MB);
  u16* qbuf   = (u16*)(ws + 80 * MB);
  u16* vtbuf  = (u16*)d_out;                   // v^T (b,h,d,t) bf16

  convq_kernel<<<dim3(48, 16), 256, 0, stream>>>(wk, wq, wv, wqkvT);
  convt3_kernel<<<dim3(16, 16, 3), 256, 0, stream>>>(wproj, w1, w2, wprojT, w1T, w2T);

  // 1) hb = LN1(x) bf16
  ln_bf16_kernel<<<NTOK/4, 256, 0, stream>>>(x, ln1g, ln1b, hb);
  // 2) k,q bf16 (bhtd) + v^T bf16 (bhdt, d_out) = hb @ WqkvF
  mgemm_kernel<0><<<3072, 256, 0, stream>>>(
      hb, wqkvT, nullptr, nullptr, (float*)vtbuf, kbuf, qbuf);
  // 3) MFMA flash attention (balanced, ILP-prefetched) -> bf16 row-major into hb
  fattn_kernel<<<B_*H_, 256, 0, stream>>>(kbuf, qbuf, vtbuf, hb);
  // 4) x1 = x + attn @ wproj + bproj -> fp32 d_out (v^T dead)
  mgemm_kernel<1><<<1024, 256, 0, stream>>>(
      hb, wprojT, bproj, x, outp, nullptr, nullptr);
  // 5) h2 = LN2(x1) bf16 (over dead k)
  ln_bf16_kernel<<<NTOK/4, 256, 0, stream>>>(outp, ln2g, ln2b, kbuf);
  // 6) ff1 = relu(h2 @ w1 + b1) bf16 (over dead q)
  mgemm_kernel<2><<<1024, 256, 0, stream>>>(
      kbuf, w1T, b1, nullptr, nullptr, qbuf, nullptr);
  // 7) out = x1 + ff1 @ w2 + b2, in-place over d_out
  mgemm_kernel<3><<<1024, 256, 0, stream>>>(
      qbuf, w2T, b2, nullptr, outp, nullptr, nullptr);
}

// Round 8
// 478.466 us; speedup vs baseline: 1.0993x; 1.0993x over previous
//
#include <hip/hip_runtime.h>

typedef unsigned int u32;
typedef unsigned short u16;
typedef __attribute__((ext_vector_type(8))) short bf16x8;   // 8 bf16 in 4 VGPRs
typedef __attribute__((ext_vector_type(4))) short bf16x4;   // 4 bf16 in 2 VGPRs
typedef __attribute__((ext_vector_type(4))) float f32x4;

#if defined(__has_builtin)
#if __has_builtin(__builtin_amdgcn_mfma_f32_16x16x16bf16_1k)
#define HAVE_MFMA16_1K 1
#endif
#endif

#define GLOBAL_AS __attribute__((address_space(1)))
#define LDS_AS    __attribute__((address_space(3)))

#define B_   64
#define T_   256
#define E_   1024
#define H_   16
#define HD_  64
#define NTOK (B_*T_)          // 16384
#define K_   1024
#define LNEPS 1e-5f

// ---------- bf16 helpers ----------
__device__ __forceinline__ u16 f2bf(float f){            // round-to-nearest-even
  u32 x = __float_as_uint(f);
  u32 r = x + 0x7fffu + ((x >> 16) & 1u);
  return (u16)(r >> 16);
}
__device__ __forceinline__ u16 f2bf_trunc(float f){      // truncate (P probs only)
  return (u16)(__float_as_uint(f) >> 16);
}
__device__ __forceinline__ u32 pack2(float a, float b){
  return (u32)f2bf(a) | ((u32)f2bf(b) << 16);
}

// async global->LDS, 16 B per lane (dest = wave-uniform base + lane*16)
__device__ __forceinline__ void gload16(const u16* g, u16* l){
  __builtin_amdgcn_global_load_lds((const GLOBAL_AS void*)g, (LDS_AS void*)l, 16, 0, 0);
}

// ---------- fused LayerNorm fp32 -> bf16, one wave per token ----------
__global__ __launch_bounds__(256) void ln_bf16_kernel(
    const float* __restrict__ x, const float* __restrict__ g,
    const float* __restrict__ b, u16* __restrict__ o)
{
  int lane  = threadIdx.x & 63;
  int token = (blockIdx.x << 2) + (threadIdx.x >> 6);
  const float4* xr = (const float4*)(x + (size_t)token * E_);
  float4 v[4];
  float s = 0.f, ss = 0.f;
  #pragma unroll
  for (int i = 0; i < 4; ++i){
    v[i] = xr[lane + 64 * i];
    s += v[i].x + v[i].y + v[i].z + v[i].w;
    ss = fmaf(v[i].x, v[i].x, fmaf(v[i].y, v[i].y,
         fmaf(v[i].z, v[i].z, fmaf(v[i].w, v[i].w, ss))));
  }
  #pragma unroll
  for (int off = 32; off > 0; off >>= 1){
    s  += __shfl_xor(s,  off);
    ss += __shfl_xor(ss, off);
  }
  float mu   = s * (1.f / E_);
  float var  = ss * (1.f / E_) - mu * mu;
  float rstd = rsqrtf(var + LNEPS);
  const float4* gr = (const float4*)g;
  const float4* br = (const float4*)b;
  uint2* orow = (uint2*)(o + (size_t)token * E_);
  #pragma unroll
  for (int i = 0; i < 4; ++i){
    float4 gg = gr[lane + 64 * i], bb = br[lane + 64 * i];
    float y0 = (v[i].x - mu) * rstd * gg.x + bb.x;
    float y1 = (v[i].y - mu) * rstd * gg.y + bb.y;
    float y2 = (v[i].z - mu) * rstd * gg.z + bb.z;
    float y3 = (v[i].w - mu) * rstd * gg.w + bb.w;
    orow[lane + 64 * i] = make_uint2(pack2(y0, y1), pack2(y2, y3));
  }
}

// ---------- weight prep: fragment-major B layout ----------
// elem(n, k) at o16 = (nb*32 + s)*2048 + j*512 + (quad*16 + l15)*8 + e
// where n = nb*64 + j*16 + l15, k = s*32 + quad*8 + e.
// z==1 (wq) is pre-scaled by 0.125 (1/sqrt(HD)) -- exact exponent shift.
__global__ __launch_bounds__(256) void convq_kernel(
    const float* __restrict__ wk, const float* __restrict__ wq,
    const float* __restrict__ wv, u16* __restrict__ o)
{
  __shared__ float tile[64 * 68];            // [k-local][d], +4 pad
  const int zh = blockIdx.x, z = zh >> 4, h = zh & 15;
  const int k0 = blockIdx.y << 6;
  const float* w = (z == 0 ? wk : z == 1 ? wq : wv) + (size_t)h * (E_ * HD_);
  const float qs = (z == 1) ? 0.125f : 1.0f;
  const int t = threadIdx.x;
  {
    int kr = t >> 2, d0 = (t & 3) << 4;
    const float4* src = (const float4*)(w + (size_t)(k0 + kr) * HD_ + d0);
    #pragma unroll
    for (int i = 0; i < 4; ++i)
      *(float4*)(tile + kr * 68 + d0 + 4 * i) = src[i];
  }
  __syncthreads();
  {
    const size_t nb32 = (size_t)zh * 32 + (k0 >> 5);   // nb == zh
    #pragma unroll
    for (int u = 0; u < 2; ++u) {
      int cid = t * 2 + u;
      int dd = cid >> 3, kc = cid & 7;
      u32 wd[4];
      #pragma unroll
      for (int e2 = 0; e2 < 4; ++e2)
        wd[e2] = pack2(qs * tile[(kc * 8 + 2 * e2) * 68 + dd],
                       qs * tile[(kc * 8 + 2 * e2 + 1) * 68 + dd]);
      u16* dst = o + (nb32 + (kc >> 2)) * 2048 + (size_t)(dd >> 4) * 512
                   + (size_t)(((kc & 3) << 4) + (dd & 15)) * 8;
      *(uint4*)dst = make_uint4(wd[0], wd[1], wd[2], wd[3]);
    }
  }
}

// w [E][E] fp32, B(n,k) = w[k][n] -> fragment-major bf16; z selects {proj,w1,w2}
__global__ __launch_bounds__(256) void convt3_kernel(
    const float* __restrict__ wp, const float* __restrict__ w1,
    const float* __restrict__ w2, u16* __restrict__ op,
    u16* __restrict__ o1, u16* __restrict__ o2)
{
  __shared__ float tile[64 * 68];            // [k-local][n-local]
  const int z = blockIdx.z;
  const float* w = (z == 0 ? wp : z == 1 ? w1 : w2);
  u16* o = (z == 0 ? op : z == 1 ? o1 : o2);
  const int n0 = blockIdx.x << 6, k0 = blockIdx.y << 6;
  const int t = threadIdx.x;
  {
    int kr = t >> 2, nn = (t & 3) << 4;
    const float4* src = (const float4*)(w + (size_t)(k0 + kr) * E_ + n0 + nn);
    #pragma unroll
    for (int i = 0; i < 4; ++i)
      *(float4*)(tile + kr * 68 + nn + 4 * i) = src[i];
  }
  __syncthreads();
  {
    const size_t nb32 = (size_t)(n0 >> 6) * 32 + (k0 >> 5);
    #pragma unroll
    for (int u = 0; u < 2; ++u) {
      int cid = t * 2 + u;
      int dd = cid >> 3, kc = cid & 7;
      u32 wd[4];
      #pragma unroll
      for (int e2 = 0; e2 < 4; ++e2)
        wd[e2] = pack2(tile[(kc * 8 + 2 * e2) * 68 + dd],
                       tile[(kc * 8 + 2 * e2 + 1) * 68 + dd]);
      u16* dst = o + (nb32 + (kc >> 2)) * 2048 + (size_t)(dd >> 4) * 512
                   + (size_t)(((kc & 3) << 4) + (dd & 15)) * 8;
      *(uint4*)dst = make_uint4(wd[0], wd[1], wd[2], wd[3]);
    }
  }
}

// ---------- MFMA GEMM: C(M x N) = A(M x 1024) * B^T, B fragment-major ----------
// (unchanged from round 6/7 -- see comments there)
#define MF4(I, AV, BV)                                                               \
  acc[I][0] = __builtin_amdgcn_mfma_f32_16x16x32_bf16(AV, BV[0], acc[I][0], 0, 0, 0);\
  acc[I][1] = __builtin_amdgcn_mfma_f32_16x16x32_bf16(AV, BV[1], acc[I][1], 0, 0, 0);\
  acc[I][2] = __builtin_amdgcn_mfma_f32_16x16x32_bf16(AV, BV[2], acc[I][2], 0, 0, 0);\
  acc[I][3] = __builtin_amdgcn_mfma_f32_16x16x32_bf16(AV, BV[3], acc[I][3], 0, 0, 0);

#define BLOADS(BV, SS) {                                                      \
    const u16* bp_ = Bp + (size_t)(SS) * 2048;                                \
    BV[0] = *(const bf16x8*)(bp_);                                            \
    BV[1] = *(const bf16x8*)(bp_ + 512);                                      \
    BV[2] = *(const bf16x8*)(bp_ + 1024);                                     \
    BV[3] = *(const bf16x8*)(bp_ + 1536);                                     \
  }

#define MSLICE2(SLOT, NSLOT, KA, DO_STAGE, DO_NXT, DO_BL, BS, ACUR, ATMP, ANXT, BV, BNV, VM) { \
    const u16* As_ = lds + (SLOT) * 4096;                                     \
    ATMP[0] = *(const bf16x8*)(As_ + aoffb + 1024);                           \
    ATMP[1] = *(const bf16x8*)(As_ + aoffb + 1536);                           \
    if (DO_STAGE) {                                                           \
      u16* d_ = lds + (((SLOT) + 3) & 3) * 4096;                              \
      gload16(Ag0 + (KA), d_ + tid * 8);                                      \
      gload16(Ag1 + (KA), d_ + 2048 + tid * 8);                               \
    }                                                                         \
    __builtin_amdgcn_s_setprio(1);                                            \
    MF4(0, ACUR[0], BV) MF4(1, ACUR[1], BV)                                   \
    __builtin_amdgcn_s_setprio(0);                                            \
    if (DO_NXT) {                                                             \
      const u16* An_ = lds + (NSLOT) * 4096;                                  \
      ANXT[0] = *(const bf16x8*)(An_ + aoffb);                                \
      ANXT[1] = *(const bf16x8*)(An_ + aoffb + 512);                          \
    }                                                                         \
    __builtin_amdgcn_s_setprio(1);                                            \
    MF4(2, ATMP[0], BV) MF4(3, ATMP[1], BV)                                   \
    __builtin_amdgcn_s_setprio(0);                                            \
    if (DO_BL) { BLOADS(BNV, BS) }                                            \
    VM;                                                                       \
    __builtin_amdgcn_s_barrier();                                             \
    __builtin_amdgcn_sched_barrier(0);                                        \
    asm volatile("" ::: "memory");                                            \
  }

#define VM10 asm volatile("s_waitcnt vmcnt(10)" ::: "memory")
#define VM8  asm volatile("s_waitcnt vmcnt(8)"  ::: "memory")
#define VM4  asm volatile("s_waitcnt vmcnt(4)"  ::: "memory")

template<int MODE>
__global__ __launch_bounds__(256, 3) void mgemm_kernel(
    const u16* __restrict__ A, const u16* __restrict__ Bt,
    const float* __restrict__ bias, const float* __restrict__ resid,
    float* __restrict__ Cf, u16* __restrict__ Cb, u16* __restrict__ Cb2)
{
  __shared__ __align__(16) u16 lds[16384];   // 32 KB: A-ring, epilogue reuse

  const int tid = threadIdx.x, lane = tid & 63, wid = tid >> 6;
  const int wm = wid >> 1, wn = wid & 1;
  const int l15 = lane & 15, quad = lane >> 4;

  // XCD-aware mapping, M-INNER intra-XCD walk.
  const int b = (int)blockIdx.x;
  const int xcd = b & 7, ib = b >> 3;
  const int mloc = ib & 15, ntile = ib >> 4;
  const int row0 = (xcd * 16 + mloc) << 7;
  const int col0 = ntile << 7;

  // A staging: pre-swizzled global source, lane-linear LDS dest.
  const int sc   = (tid & 7) ^ ((tid >> 3) & 7);
  const int srow = 2 * (tid >> 3) + (sc >> 2);          // 0..63
  const int skof = (sc & 3) << 3;
  const u16* Ag0 = A + (size_t)(row0 + srow) * K_ + skof;
  const u16* Ag1 = Ag0 + (size_t)64 * K_;

  // A fragment read offsets (paired-row + 3-bit XOR)
  const int rhalf = l15 >> 1;
  const int cph   = ((((l15 & 1) << 2) | quad) ^ rhalf);
  const int aoffb = wm * 2048 + rhalf * 64 + cph * 8;

  // B fragment-major pointer: nb = col0/64 + wn
  const u16* Bp = Bt + (size_t)((col0 >> 6) + wn) * 65536 + lane * 8;

  f32x4 acc[4][4];
  #pragma unroll
  for (int i = 0; i < 4; ++i)
    #pragma unroll
    for (int j = 0; j < 4; ++j)
      acc[i][j] = (f32x4){0.f, 0.f, 0.f, 0.f};

  bf16x8 aA[2], aB[2], aT[2], bE[4], bO[4];

  #pragma unroll
  for (int t3 = 0; t3 < 3; ++t3) {
    u16* d_ = lds + t3 * 4096;
    gload16(Ag0 + t3 * 32, d_ + tid * 8);
    gload16(Ag1 + t3 * 32, d_ + 2048 + tid * 8);
  }
  BLOADS(bE, 0)
  BLOADS(bO, 1)
  asm volatile("s_waitcnt vmcnt(10)" ::: "memory");
  __builtin_amdgcn_s_barrier();
  __builtin_amdgcn_sched_barrier(0);
  asm volatile("" ::: "memory");

  aA[0] = *(const bf16x8*)(lds + aoffb);
  aA[1] = *(const bf16x8*)(lds + aoffb + 512);

  #pragma unroll 1
  for (int s = 0; s < 28; s += 2) {
    MSLICE2(s & 3, (s + 1) & 3, (s + 3) * 32, 1, 1, 1, s + 2, aA, aT, aB, bE, bE, VM10)
    MSLICE2((s + 1) & 3, (s + 2) & 3, (s + 4) * 32, 1, 1, 1, s + 3, aB, aT, aA, bO, bO, VM10)
  }
  MSLICE2(0, 1, 31 * 32, 1, 1, 1, 30, aA, aT, aB, bE, bE, VM10)   // s=28
  MSLICE2(1, 2, 0,       0, 1, 1, 31, aB, aT, aA, bO, bO, VM8 )   // s=29
  MSLICE2(2, 3, 0,       0, 1, 0, 0,  aA, aT, aB, bE, bE, VM4 )   // s=30
  MSLICE2(3, 0, 0,       0, 0, 0, 0,  aB, aT, aA, bO, bO, (void)0)// s=31

  if (MODE == 1 || MODE == 3) {
    const int rbase = row0 + wm * 64;
    #pragma unroll
    for (int j = 0; j < 4; ++j) {
      const int n = col0 + wn * 64 + j * 16 + l15;
      const float bn = bias[n];
      #pragma unroll
      for (int i = 0; i < 4; ++i)
        #pragma unroll
        for (int r = 0; r < 4; ++r) {
          const int row = rbase + i * 16 + quad * 4 + r;
          const size_t idx = (size_t)row * E_ + n;
          float v = acc[i][j][r] + bn;
          if (MODE == 1) Cf[idx] = v + resid[idx];
          else           Cf[idx] = v + Cf[idx];
        }
    }
    return;
  }

  u16* ep = lds + wid * 4096;                  // 64x64 u16, row stride 64
  const int nb0 = col0 + wn * 64;

  if (MODE == 2) {
    #pragma unroll
    for (int j = 0; j < 4; ++j) {
      const float bn = bias[nb0 + j * 16 + l15];
      #pragma unroll
      for (int i = 0; i < 4; ++i)
        #pragma unroll
        for (int r = 0; r < 4; ++r)
          ep[(i*16 + quad*4 + r) * 64 + j*16 + l15] =
              f2bf(fmaxf(acc[i][j][r] + bn, 0.f));
    }
    const int rbase = row0 + wm * 64;
    #pragma unroll
    for (int it = 0; it < 8; ++it) {
      const int tl = it * 8 + (lane >> 3), c = lane & 7;
      uint4 v = *(const uint4*)(ep + tl * 64 + c * 8);
      *(uint4*)(Cb + (size_t)(rbase + tl) * E_ + nb0 + c * 8) = v;
    }
    return;
  }

  const int z = nb0 >> 10, hh = (nb0 >> 6) & 15;
  const int rows0 = row0 + wm * 64;
  const int bb = rows0 >> 8, tb = rows0 & 255;
  if (z < 2) {
    #pragma unroll
    for (int i = 0; i < 4; ++i)
      #pragma unroll
      for (int j = 0; j < 4; ++j)
        #pragma unroll
        for (int r = 0; r < 4; ++r)
          ep[(i*16 + quad*4 + r) * 64 + j*16 + l15] = f2bf(acc[i][j][r]);
    u16* out = (z == 0 ? Cb : Cb2) + ((size_t)(bb * H_ + hh) * T_ + tb) * HD_;
    #pragma unroll
    for (int it = 0; it < 8; ++it) {
      const int tl = it * 8 + (lane >> 3), c = lane & 7;
      uint4 v = *(const uint4*)(ep + tl * 64 + c * 8);
      *(uint4*)(out + (size_t)tl * HD_ + c * 8) = v;
    }
  } else {
    #pragma unroll
    for (int i = 0; i < 4; ++i)
      #pragma unroll
      for (int j = 0; j < 4; ++j)
        #pragma unroll
        for (int r = 0; r < 4; ++r) {
          const int tl = i*16 + quad*4 + r, d = j*16 + l15;
          const int cs = (tl >> 3) ^ (d & 7);
          ep[d * 64 + cs * 8 + (tl & 7)] = f2bf(acc[i][j][r]);
        }
    u16* out = (u16*)Cf + ((size_t)(bb * H_ + hh) * HD_) * T_;
    #pragma unroll
    for (int it = 0; it < 8; ++it) {
      const int d = it * 8 + (lane >> 3), c = lane & 7;
      const int cs = c ^ (d & 7);
      uint4 v = *(const uint4*)(ep + d * 64 + cs * 8);
      *(uint4*)(out + (size_t)d * T_ + tb + c * 8) = v;
    }
  }
}

// ---------- MFMA flash attention, swapped-QK^T (S^T in registers) ----------
// scores[t][s] = k_t . q_s (q pre-scaled by 1/8), causal s<=t.
// Swapped: ST[j][i] = mfma(qf[j], kf[i]) -> lane holds S^T[s=j*16+quad*4+r]
// [t=i*16+l15].  Softmax per t-column: 15 in-reg fmax + 2 shfl (vs 128 shfl).
// P^T register layout IS the B-operand of mfma_f32_16x16x16bf16_1k -> PV runs
// straight from registers (no LDS round-trip); V^T is the A-operand (d=l15).
// Accumulator is O^T[d][t]; one LDS transpose at the end.
// Block = 4 waves at the SAME tblk (uniform work); tblk = 3 - blockIdx.y so
// longest blocks dispatch first (LPT).  launch_bounds(256,2): 2 waves/SIMD.
__global__ __launch_bounds__(256, 2) void fattn_kernel(
    const u16* __restrict__ kk_, const u16* __restrict__ qq_,
    const u16* __restrict__ vt_, u16* __restrict__ out)
{
  __shared__ __align__(16) u16 Pb[4][64 * 72];  // per-wave private (final transpose)
  const int tid = threadIdx.x, lane = tid & 63, wv = tid >> 6;
  const int bh = blockIdx.x * 4 + wv;
  const int tblk = 3 - (int)blockIdx.y;
  const int l15 = lane & 15, quad = lane >> 4;
  const u16* kb  = kk_ + (size_t)bh * (T_ * HD_);
  const u16* qb  = qq_ + (size_t)bh * (T_ * HD_);
  const u16* vtb = vt_ + (size_t)bh * (HD_ * T_);
  u16* Pw = Pb[wv];

  // K fragments: B-operand (n = t = l15, k = quad*8+e)
  bf16x8 kf[4][2];
  #pragma unroll
  for (int i = 0; i < 4; ++i)
    #pragma unroll
    for (int c = 0; c < 2; ++c)
      kf[i][c] = *(const bf16x8*)(kb + (size_t)(tblk*64 + i*16 + l15) * HD_ + c*32 + quad*8);

  // Q fragments: A-operand (m = s = l15, k = quad*8+e), persistent + prefetch
  bf16x8 qf[4][2];
  #pragma unroll
  for (int j = 0; j < 4; ++j)
    #pragma unroll
    for (int c = 0; c < 2; ++c)
      qf[j][c] = *(const bf16x8*)(qb + (size_t)(j*16 + l15) * HD_ + c*32 + quad*8);

  f32x4 accT[4][4];            // [jd][i]: O^T[d=jd*16+quad*4+r][t=i*16+l15]
  float mrow[4], lrow[4];      // per t-column (i)
  #pragma unroll
  for (int i = 0; i < 4; ++i) {
    #pragma unroll
    for (int jd = 0; jd < 4; ++jd) accT[jd][i] = (f32x4){0.f, 0.f, 0.f, 0.f};
    mrow[i] = -1e30f; lrow[i] = 0.f;
  }

  for (int sb = 0; sb <= tblk; ++sb) {
    // ---- S^T = (Q/8) . K^T, swapped operands ----
    f32x4 ST[4][4];            // [j][i]
    __builtin_amdgcn_s_setprio(1);
    #pragma unroll
    for (int j = 0; j < 4; ++j)
      #pragma unroll
      for (int i = 0; i < 4; ++i) {
        f32x4 t0 = __builtin_amdgcn_mfma_f32_16x16x32_bf16(qf[j][0], kf[i][0],
                       (f32x4){0.f,0.f,0.f,0.f}, 0, 0, 0);
        ST[j][i] = __builtin_amdgcn_mfma_f32_16x16x32_bf16(qf[j][1], kf[i][1], t0, 0, 0, 0);
      }
    __builtin_amdgcn_s_setprio(0);
    // ---- prefetch Q(sb+1) (anti-dep on qf orders after the MFMAs) ----
    if (sb < tblk) {
      #pragma unroll
      for (int j = 0; j < 4; ++j)
        #pragma unroll
        for (int c = 0; c < 2; ++c)
          qf[j][c] = *(const bf16x8*)(qb + (size_t)((sb+1)*64 + j*16 + l15) * HD_ + c*32 + quad*8);
    }
    // ---- V loads for this sb (consumed after softmax; latency hidden) ----
#ifdef HAVE_MFMA16_1K
    bf16x4 vv[4][4];           // [j][jd]: A-op (m=d=l15, k=s_loc=quad*4+e)
    #pragma unroll
    for (int j = 0; j < 4; ++j)
      #pragma unroll
      for (int jd = 0; jd < 4; ++jd)
        vv[j][jd] = *(const bf16x4*)(vtb + (size_t)(jd*16 + l15) * T_ + sb*64 + j*16 + quad*4);
#else
    bf16x8 vf[4][2];           // [jd][c]: A-op (m=d=l15, k=s=c*32+quad*8+e)
    #pragma unroll
    for (int jd = 0; jd < 4; ++jd)
      #pragma unroll
      for (int c = 0; c < 2; ++c)
        vf[jd][c] = *(const bf16x8*)(vtb + (size_t)(jd*16 + l15) * T_ + sb*64 + c*32 + quad*8);
#endif
    // ---- causal mask (diagonal block only) ----
    if (sb == tblk) {
      #pragma unroll
      for (int j = 0; j < 4; ++j)
        #pragma unroll
        for (int i = 0; i < 4; ++i)
          #pragma unroll
          for (int r = 0; r < 4; ++r)
            if (j*16 + quad*4 + r > i*16 + l15) ST[j][i][r] = -1e30f;
    }
    // ---- online softmax per t-column ----
    #pragma unroll
    for (int i = 0; i < 4; ++i) {
      float mx = ST[0][i][0];
      #pragma unroll
      for (int j = 0; j < 4; ++j)
        #pragma unroll
        for (int r = 0; r < 4; ++r) mx = fmaxf(mx, ST[j][i][r]);
      mx = fmaxf(mx, __shfl_xor(mx, 16));
      mx = fmaxf(mx, __shfl_xor(mx, 32));
      float mn = fmaxf(mrow[i], mx);
      float al = __expf(mrow[i] - mn);
      mrow[i] = mn;
      float sm = 0.f;
      #pragma unroll
      for (int j = 0; j < 4; ++j)
        #pragma unroll
        for (int r = 0; r < 4; ++r) {
          float p = __expf(ST[j][i][r] - mn);
          ST[j][i][r] = p;
          sm += p;
        }
      sm += __shfl_xor(sm, 16);
      sm += __shfl_xor(sm, 32);
      lrow[i] = lrow[i] * al + sm;
      #pragma unroll
      for (int jd = 0; jd < 4; ++jd) accT[jd][i] = accT[jd][i] * al;
    }
#ifdef HAVE_MFMA16_1K
    // ---- PV straight from registers: O^T += V^T . P^T ----
    #pragma unroll
    for (int j = 0; j < 4; ++j) {
      bf16x4 pfj[4];
      #pragma unroll
      for (int i = 0; i < 4; ++i)
        pfj[i] = (bf16x4){(short)f2bf_trunc(ST[j][i][0]), (short)f2bf_trunc(ST[j][i][1]),
                          (short)f2bf_trunc(ST[j][i][2]), (short)f2bf_trunc(ST[j][i][3])};
      __builtin_amdgcn_s_setprio(1);
      #pragma unroll
      for (int jd = 0; jd < 4; ++jd)
        #pragma unroll
        for (int i = 0; i < 4; ++i)
          accT[jd][i] = __builtin_amdgcn_mfma_f32_16x16x16bf16_1k(
              vv[j][jd], pfj[i], accT[jd][i], 0, 0, 0);
      __builtin_amdgcn_s_setprio(0);
    }
#else
    // ---- fallback: P^T via LDS [t][s], B-operand reads; same O^T layout ----
    #pragma unroll
    for (int j = 0; j < 4; ++j)
      #pragma unroll
      for (int i = 0; i < 4; ++i)
        #pragma unroll
        for (int r = 0; r < 4; ++r)
          Pw[(i*16 + l15) * 72 + j*16 + quad*4 + r] = f2bf_trunc(ST[j][i][r]);
    bf16x8 pfB[4][2];
    #pragma unroll
    for (int i = 0; i < 4; ++i)
      #pragma unroll
      for (int c = 0; c < 2; ++c)
        pfB[i][c] = *(const bf16x8*)(Pw + (i*16 + l15) * 72 + c*32 + quad*8);
    __builtin_amdgcn_s_setprio(1);
    #pragma unroll
    for (int jd = 0; jd < 4; ++jd)
      #pragma unroll
      for (int i = 0; i < 4; ++i) {
        f32x4 t0 = __builtin_amdgcn_mfma_f32_16x16x32_bf16(vf[jd][0], pfB[i][0], accT[jd][i], 0, 0, 0);
        accT[jd][i] = __builtin_amdgcn_mfma_f32_16x16x32_bf16(vf[jd][1], pfB[i][1], t0, 0, 0, 0);
      }
    __builtin_amdgcn_s_setprio(0);
#endif
  }

  // ---- normalize, transpose O^T -> [t][d] via private LDS, coalesced store ----
  #pragma unroll
  for (int i = 0; i < 4; ++i) {
    float inv = 1.0f / lrow[i];
    #pragma unroll
    for (int jd = 0; jd < 4; ++jd)
      #pragma unroll
      for (int r = 0; r < 4; ++r)
        Pw[(i*16 + l15) * 72 + jd*16 + quad*4 + r] = f2bf(accT[jd][i][r] * inv);
  }
  {
    const int b = bh >> 4, h = bh & 15;
    const uint4* pr = (const uint4*)(Pw + lane * 72);
    uint4* og = (uint4*)(out + ((size_t)(b * T_ + tblk*64 + lane)) * E_ + h * HD_);
    #pragma unroll
    for (int k = 0; k < 8; ++k) og[k] = pr[k];
  }
}

// ---------- launch ----------
extern "C" void kernel_launch(void* const* d_in, const int* in_sizes, int n_in,
                              void* d_out, int out_size, void* d_ws, size_t ws_size,
                              hipStream_t stream) {
  const float* x     = (const float*)d_in[0];
  const float* ln1g  = (const float*)d_in[1];
  const float* ln1b  = (const float*)d_in[2];
  const float* wk    = (const float*)d_in[3];
  const float* wq    = (const float*)d_in[4];
  const float* wv    = (const float*)d_in[5];
  const float* wproj = (const float*)d_in[6];
  const float* bproj = (const float*)d_in[7];
  const float* ln2g  = (const float*)d_in[8];
  const float* ln2b  = (const float*)d_in[9];
  const float* w1    = (const float*)d_in[10];
  const float* b1    = (const float*)d_in[11];
  const float* w2    = (const float*)d_in[12];
  const float* b2    = (const float*)d_in[13];
  float* outp = (float*)d_out;

  // ws (112 MB <= proven 128 MB):
  //  [0,6M) WqkvF | [6,8M) WprojF | [8,10M) W1F | [10,12M) W2F   (fragment-major)
  //  [16,48M) hb bf16 (LN1 out -> attn out)
  //  [48,80M) k bf16 (bhtd) -> h2 bf16 | [80,112M) q bf16 (bhtd) -> ff1 bf16
  // d_out (64MB): v^T bf16 (b,h,d,t) [0,32M) -> x1 fp32 (full) -> out (in-place)
  char* ws = (char*)d_ws;
  const size_t MB = 1024 * 1024;
  u16* wqkvT  = (u16*)(ws);
  u16* wprojT = (u16*)(ws + 6 * MB);
  u16* w1T    = (u16*)(ws + 8 * MB);
  u16* w2T    = (u16*)(ws + 10 * MB);
  u16* hb     = (u16*)(ws + 16 * MB);
  u16* kbuf   = (u16*)(ws + 48 * MB);
  u16* qbuf   = (u16*)(ws + 80 * MB);
  u16* vtbuf  = (u16*)d_out;                   // v^T (b,h,d,t) bf16

  convq_kernel<<<dim3(48, 16), 256, 0, stream>>>(wk, wq, wv, wqkvT);
  convt3_kernel<<<dim3(16, 16, 3), 256, 0, stream>>>(wproj, w1, w2, wprojT, w1T, w2T);

  // 1) hb = LN1(x) bf16
  ln_bf16_kernel<<<NTOK/4, 256, 0, stream>>>(x, ln1g, ln1b, hb);
  // 2) k,q bf16 (bhtd; q pre-scaled by 1/8) + v^T bf16 (bhdt, d_out) = hb @ WqkvF
  mgemm_kernel<0><<<3072, 256, 0, stream>>>(
      hb, wqkvT, nullptr, nullptr, (float*)vtbuf, kbuf, qbuf);
  // 3) MFMA flash attention (swapped, reg-resident P) -> bf16 row-major into hb
  fattn_kernel<<<dim3(B_*H_/4, 4), 256, 0, stream>>>(kbuf, qbuf, vtbuf, hb);
  // 4) x1 = x + attn @ wproj + bproj -> fp32 d_out (v^T dead)
  mgemm_kernel<1><<<1024, 256, 0, stream>>>(
      hb, wprojT, bproj, x, outp, nullptr, nullptr);
  // 5) h2 = LN2(x1) bf16 (over dead k)
  ln_bf16_kernel<<<NTOK/4, 256, 0, stream>>>(outp, ln2g, ln2b, kbuf);
  // 6) ff1 = relu(h2 @ w1 + b1) bf16 (over dead q)
  mgemm_kernel<2><<<1024, 256, 0, stream>>>(
      kbuf, w1T, b1, nullptr, nullptr, qbuf, nullptr);
  // 7) out = x1 + ff1 @ w2 + b2, in-place over d_out
  mgemm_kernel<3><<<1024, 256, 0, stream>>>(
      qbuf, w2T, b2, nullptr, outp, nullptr, nullptr);
}

// Round 11
// 468.359 us; speedup vs baseline: 1.1230x; 1.0216x over previous
//
#include <hip/hip_runtime.h>

typedef unsigned int u32;
typedef unsigned short u16;
typedef __attribute__((ext_vector_type(8))) short bf16x8;   // 8 bf16 in 4 VGPRs
typedef __attribute__((ext_vector_type(4))) short bf16x4;   // 4 bf16 in 2 VGPRs
typedef __attribute__((ext_vector_type(4))) float f32x4;

#if defined(__has_builtin)
#if __has_builtin(__builtin_amdgcn_mfma_f32_16x16x16bf16_1k)
#define HAVE_MFMA16_1K 1
#endif
#endif

#define GLOBAL_AS __attribute__((address_space(1)))
#define LDS_AS    __attribute__((address_space(3)))

#define B_   64
#define T_   256
#define E_   1024
#define H_   16
#define HD_  64
#define NTOK (B_*T_)          // 16384
#define K_   1024
#define LNEPS 1e-5f

// ---------- bf16 helpers ----------
__device__ __forceinline__ u16 f2bf(float f){            // round-to-nearest-even
  u32 x = __float_as_uint(f);
  u32 r = x + 0x7fffu + ((x >> 16) & 1u);
  return (u16)(r >> 16);
}
__device__ __forceinline__ u16 f2bf_trunc(float f){      // truncate (P probs only)
  return (u16)(__float_as_uint(f) >> 16);
}
__device__ __forceinline__ u32 pack2(float a, float b){
  return (u32)f2bf(a) | ((u32)f2bf(b) << 16);
}

// async global->LDS, 16 B per lane (dest = wave-uniform base + lane*16)
__device__ __forceinline__ void gload16(const u16* g, u16* l){
  __builtin_amdgcn_global_load_lds((const GLOBAL_AS void*)g, (LDS_AS void*)l, 16, 0, 0);
}

// ---------- fused LayerNorm fp32 -> bf16, one wave per token ----------
__global__ __launch_bounds__(256) void ln_bf16_kernel(
    const float* __restrict__ x, const float* __restrict__ g,
    const float* __restrict__ b, u16* __restrict__ o)
{
  int lane  = threadIdx.x & 63;
  int token = (blockIdx.x << 2) + (threadIdx.x >> 6);
  const float4* xr = (const float4*)(x + (size_t)token * E_);
  float4 v[4];
  float s = 0.f, ss = 0.f;
  #pragma unroll
  for (int i = 0; i < 4; ++i){
    v[i] = xr[lane + 64 * i];
    s += v[i].x + v[i].y + v[i].z + v[i].w;
    ss = fmaf(v[i].x, v[i].x, fmaf(v[i].y, v[i].y,
         fmaf(v[i].z, v[i].z, fmaf(v[i].w, v[i].w, ss))));
  }
  #pragma unroll
  for (int off = 32; off > 0; off >>= 1){
    s  += __shfl_xor(s,  off);
    ss += __shfl_xor(ss, off);
  }
  float mu   = s * (1.f / E_);
  float var  = ss * (1.f / E_) - mu * mu;
  float rstd = rsqrtf(var + LNEPS);
  const float4* gr = (const float4*)g;
  const float4* br = (const float4*)b;
  uint2* orow = (uint2*)(o + (size_t)token * E_);
  #pragma unroll
  for (int i = 0; i < 4; ++i){
    float4 gg = gr[lane + 64 * i], bb = br[lane + 64 * i];
    float y0 = (v[i].x - mu) * rstd * gg.x + bb.x;
    float y1 = (v[i].y - mu) * rstd * gg.y + bb.y;
    float y2 = (v[i].z - mu) * rstd * gg.z + bb.z;
    float y3 = (v[i].w - mu) * rstd * gg.w + bb.w;
    orow[lane + 64 * i] = make_uint2(pack2(y0, y1), pack2(y2, y3));
  }
}

// ---------- weight prep: fragment-major B layout ----------
// elem(n, k) at o16 = (nb*32 + s)*2048 + j*512 + (quad*16 + l15)*8 + e
// where n = nb*64 + j*16 + l15, k = s*32 + quad*8 + e.
// z==1 (wq) pre-scaled by 0.125 (1/sqrt(HD)) -- exact exponent shift.
__global__ __launch_bounds__(256) void convq_kernel(
    const float* __restrict__ wk, const float* __restrict__ wq,
    const float* __restrict__ wv, u16* __restrict__ o)
{
  __shared__ float tile[64 * 68];            // [k-local][d], +4 pad
  const int zh = blockIdx.x, z = zh >> 4, h = zh & 15;
  const int k0 = blockIdx.y << 6;
  const float* w = (z == 0 ? wk : z == 1 ? wq : wv) + (size_t)h * (E_ * HD_);
  const float qs = (z == 1) ? 0.125f : 1.0f;
  const int t = threadIdx.x;
  {
    int kr = t >> 2, d0 = (t & 3) << 4;
    const float4* src = (const float4*)(w + (size_t)(k0 + kr) * HD_ + d0);
    #pragma unroll
    for (int i = 0; i < 4; ++i)
      *(float4*)(tile + kr * 68 + d0 + 4 * i) = src[i];
  }
  __syncthreads();
  {
    const size_t nb32 = (size_t)zh * 32 + (k0 >> 5);   // nb == zh
    #pragma unroll
    for (int u = 0; u < 2; ++u) {
      int cid = t * 2 + u;
      int dd = cid >> 3, kc = cid & 7;
      u32 wd[4];
      #pragma unroll
      for (int e2 = 0; e2 < 4; ++e2)
        wd[e2] = pack2(qs * tile[(kc * 8 + 2 * e2) * 68 + dd],
                       qs * tile[(kc * 8 + 2 * e2 + 1) * 68 + dd]);
      u16* dst = o + (nb32 + (kc >> 2)) * 2048 + (size_t)(dd >> 4) * 512
                   + (size_t)(((kc & 3) << 4) + (dd & 15)) * 8;
      *(uint4*)dst = make_uint4(wd[0], wd[1], wd[2], wd[3]);
    }
  }
}

// w [E][E] fp32, B(n,k) = w[k][n] -> fragment-major bf16; z selects {proj,w1,w2}
__global__ __launch_bounds__(256) void convt3_kernel(
    const float* __restrict__ wp, const float* __restrict__ w1,
    const float* __restrict__ w2, u16* __restrict__ op,
    u16* __restrict__ o1, u16* __restrict__ o2)
{
  __shared__ float tile[64 * 68];            // [k-local][n-local]
  const int z = blockIdx.z;
  const float* w = (z == 0 ? wp : z == 1 ? w1 : w2);
  u16* o = (z == 0 ? op : z == 1 ? o1 : o2);
  const int n0 = blockIdx.x << 6, k0 = blockIdx.y << 6;
  const int t = threadIdx.x;
  {
    int kr = t >> 2, nn = (t & 3) << 4;
    const float4* src = (const float4*)(w + (size_t)(k0 + kr) * E_ + n0 + nn);
    #pragma unroll
    for (int i = 0; i < 4; ++i)
      *(float4*)(tile + kr * 68 + nn + 4 * i) = src[i];
  }
  __syncthreads();
  {
    const size_t nb32 = (size_t)(n0 >> 6) * 32 + (k0 >> 5);
    #pragma unroll
    for (int u = 0; u < 2; ++u) {
      int cid = t * 2 + u;
      int dd = cid >> 3, kc = cid & 7;
      u32 wd[4];
      #pragma unroll
      for (int e2 = 0; e2 < 4; ++e2)
        wd[e2] = pack2(tile[(kc * 8 + 2 * e2) * 68 + dd],
                       tile[(kc * 8 + 2 * e2 + 1) * 68 + dd]);
      u16* dst = o + (nb32 + (kc >> 2)) * 2048 + (size_t)(dd >> 4) * 512
                   + (size_t)(((kc & 3) << 4) + (dd & 15)) * 8;
      *(uint4*)dst = make_uint4(wd[0], wd[1], wd[2], wd[3]);
    }
  }
}

// ---------- MFMA GEMM, 8-phase class: 256x256 tile / 512 thr (8 waves 2Mx4N) ----------
// Per-wave 128x64 C (acc[8][4]).  A-only LDS: BK=64 K-tiles, double-buffered
// (2 x 32 KB = 64 KB) -> 2 blocks/CU co-resident.  B fragment-major in regs.
// Per K-tile: 4 phases of {4 ds_read || staging -> 16 MFMA}, ONE barrier/tile,
// vmcnt(8) once per tile (never 0 mid-loop).  sched_barrier(0x38F) pins VMEM
// issue order (A-gloads before B-loads) so the vmcnt count is sound.
// ALL register reloads (aX/aY/bE/bO) are placed AFTER their last MFMA use
// (round-9 bug: bO reloaded before its second MFMA cluster -> wrong B panel).
// LDS layout per 128-row half: paired-row 16B chunks, slot = ((r&1)*8+c)^(pr&15)
// at off16 = pr*128 + slot*8 (pr=r>>1, c=k>>3) -> ds_read_b128 is 2-way (free);
// staged via lane-linear gload16 with the inverse perm on the global source.
// MODE 0: qkv -> k,q bf16 (b,h,t,d); v bf16 TRANSPOSED (b,h,d,t)
// MODE 1: proj -> Cf fp32 = acc + bias + resid              [row-major]
// MODE 2: ff1  -> Cb bf16 = relu(acc + bias)
// MODE 3: ff2  -> Cf fp32 = acc + bias + Cf (in-place residual)
#define MF4(I, AV, BV)                                                               \
  acc[I][0] = __builtin_amdgcn_mfma_f32_16x16x32_bf16(AV, BV[0], acc[I][0], 0, 0, 0);\
  acc[I][1] = __builtin_amdgcn_mfma_f32_16x16x32_bf16(AV, BV[1], acc[I][1], 0, 0, 0);\
  acc[I][2] = __builtin_amdgcn_mfma_f32_16x16x32_bf16(AV, BV[2], acc[I][2], 0, 0, 0);\
  acc[I][3] = __builtin_amdgcn_mfma_f32_16x16x32_bf16(AV, BV[3], acc[I][3], 0, 0, 0);

#define MC(IB, AV, BV)                                                        \
    __builtin_amdgcn_s_setprio(1);                                            \
    MF4((IB)+0, AV[0], BV) MF4((IB)+1, AV[1], BV)                             \
    MF4((IB)+2, AV[2], BV) MF4((IB)+3, AV[3], BV)                             \
    __builtin_amdgcn_s_setprio(0);

#define BLOADS(BV, SS) {                                                      \
    const u16* bp_ = Bp + (size_t)(SS) * 2048;                                \
    BV[0] = *(const bf16x8*)(bp_);                                            \
    BV[1] = *(const bf16x8*)(bp_ + 512);                                      \
    BV[2] = *(const bf16x8*)(bp_ + 1024);                                     \
    BV[3] = *(const bf16x8*)(bp_ + 1536);                                     \
  }

// 4 A-fragment reads (i = IB..IB+3, slot S for even i, S^8 for odd i)
#define ARD4(DST, AB, IB, S)                                                  \
    DST[0] = *(const bf16x8*)((AB) + ((IB)+0)*1024 + prl*128 + (S)*8);        \
    DST[1] = *(const bf16x8*)((AB) + ((IB)+1)*1024 + prl*128 + ((S)^8)*8);    \
    DST[2] = *(const bf16x8*)((AB) + ((IB)+2)*1024 + prl*128 + (S)*8);        \
    DST[3] = *(const bf16x8*)((AB) + ((IB)+3)*1024 + prl*128 + ((S)^8)*8);

#define GTILE(T, DOS) {                                                       \
    const int d_ = (T) & 1;                                                   \
    const u16* Ab = lds + d_*16384 + wm*8192;                                 \
    u16* sd = lds + (d_^1)*16384;                                             \
    ARD4(aX, Ab, 0, s00v)                                                     \
    if (DOS) { gload16(Ag00 + ((T)+1)*64, sd + tid*8);                        \
               gload16(Ag01 + ((T)+1)*64, sd + 4096 + tid*8); }               \
    ARD4(aY, Ab, 4, s00v)                                                     \
    if (DOS) { gload16(Ag10 + ((T)+1)*64, sd + 8192 + tid*8);                 \
               gload16(Ag11 + ((T)+1)*64, sd + 12288 + tid*8);                \
               __builtin_amdgcn_sched_barrier(0x38F); }                       \
    MC(0, aX, bE)                                                             \
    ARD4(aX, Ab, 0, s01v)                                                     \
    MC(4, aY, bE)                                                             \
    if (DOS) { BLOADS(bE, 2*(T)+2) }                                          \
    ARD4(aY, Ab, 4, s01v)                                                     \
    MC(0, aX, bO)                                                             \
    MC(4, aY, bO)                                                             \
    if (DOS) { BLOADS(bO, 2*(T)+3)                                            \
               asm volatile("s_waitcnt vmcnt(8)" ::: "memory"); }             \
    __builtin_amdgcn_s_barrier();                                             \
    __builtin_amdgcn_sched_barrier(0);                                        \
    asm volatile("" ::: "memory");                                            \
  }

template<int MODE>
__global__ __launch_bounds__(512, 2) void mgemm_kernel(
    const u16* __restrict__ A, const u16* __restrict__ Bt,
    const float* __restrict__ bias, const float* __restrict__ resid,
    float* __restrict__ Cf, u16* __restrict__ Cb, u16* __restrict__ Cb2)
{
  __shared__ __align__(16) u16 lds[32768];   // 64 KB: A dbuf, epilogue reuse

  const int tid = threadIdx.x, lane = tid & 63, wid = tid >> 6;
  const int wm = wid >> 2, wn = wid & 3;
  const int l15 = lane & 15, quad = lane >> 4;

  // XCD-aware mapping, M-INNER intra-XCD walk (8 M-tiles of 256 rows per XCD).
  const int b = (int)blockIdx.x;
  const int xcd = b & 7, ib = b >> 3;
  const int mloc = ib & 7, ntile = ib >> 3;
  const int row0 = (xcd * 8 + mloc) << 8;
  const int col0 = ntile << 8;

  // A staging source (inverse of the paired-row LDS perm), lane-linear dest.
  // chunk cid = n*512 + tid: pr=cid>>4, sp=(cid&15)^(pr&15), r=2pr+(sp>>3), c=sp&7
  const int cid1 = 512 + tid;
  const int pr0 = tid >> 4,  sp0 = (tid & 15)  ^ (pr0 & 15);
  const int pr1 = cid1 >> 4, sp1 = (cid1 & 15) ^ (pr1 & 15);
  const int r0 = 2*pr0 + (sp0 >> 3), c0 = sp0 & 7;
  const int r1 = 2*pr1 + (sp1 >> 3), c1 = sp1 & 7;
  const u16* Ag00 = A + (size_t)(row0 + r0) * K_ + c0 * 8;
  const u16* Ag01 = A + (size_t)(row0 + r1) * K_ + c1 * 8;
  const u16* Ag10 = Ag00 + (size_t)128 * K_;
  const u16* Ag11 = Ag01 + (size_t)128 * K_;

  // A fragment read constants
  const int prl  = l15 >> 1;
  const int s00v = (((l15 & 1) << 3) + quad) ^ prl;        // kk = 0
  const int s01v = (((l15 & 1) << 3) + 4 + quad) ^ prl;    // kk = 1

  // B fragment-major pointer: nb = col0/64 + wn
  const u16* Bp = Bt + (size_t)((col0 >> 6) + wn) * 65536 + lane * 8;

  f32x4 acc[8][4];
  #pragma unroll
  for (int i = 0; i < 8; ++i)
    #pragma unroll
    for (int j = 0; j < 4; ++j)
      acc[i][j] = (f32x4){0.f, 0.f, 0.f, 0.f};

  bf16x8 aX[4], aY[4], bE[4], bO[4];

  // prologue: stage tile 0 (4 gloads), then B(0),B(1) (8 loads); vmcnt(8)
  // leaves the B loads in flight while guaranteeing tile 0 is staged.
  gload16(Ag00, lds + tid * 8);
  gload16(Ag01, lds + 4096 + tid * 8);
  gload16(Ag10, lds + 8192 + tid * 8);
  gload16(Ag11, lds + 12288 + tid * 8);
  __builtin_amdgcn_sched_barrier(0x38F);
  BLOADS(bE, 0)
  BLOADS(bO, 1)
  asm volatile("s_waitcnt vmcnt(8)" ::: "memory");
  __builtin_amdgcn_s_barrier();
  __builtin_amdgcn_sched_barrier(0);
  asm volatile("" ::: "memory");

  // 16 K-tiles of BK=64; tile t stages tile t+1 and loads B(t+1).
  #pragma unroll 1
  for (int t = 0; t < 15; ++t) GTILE(t, 1)
  GTILE(15, 0)

  if (MODE == 1 || MODE == 3) {
    // fp32 row-major epilogue (dword-coalesced scalar stores)
    const int rbase = row0 + wm * 128;
    #pragma unroll
    for (int j = 0; j < 4; ++j) {
      const int n = col0 + wn * 64 + j * 16 + l15;
      const float bn = bias[n];
      #pragma unroll
      for (int i = 0; i < 8; ++i)
        #pragma unroll
        for (int r = 0; r < 4; ++r) {
          const int row = rbase + i * 16 + quad * 4 + r;
          const size_t idx = (size_t)row * E_ + n;
          float v = acc[i][j][r] + bn;
          if (MODE == 1) Cf[idx] = v + resid[idx];
          else           Cf[idx] = v + Cf[idx];
        }
    }
    return;
  }

  // ---- bf16 epilogues: per-wave 8-KB LDS transpose, TWO 64-row passes ----
  // (tile15's end barrier guarantees all LDS reads done; ep regions are
  //  per-wave private so no further barriers are needed)
  u16* ep = lds + wid * 4096;                  // 64x64 u16, row stride 64
  const int nb0 = col0 + wn * 64;              // wave's 64-col window

  if (MODE == 2) {
    const int rbase = row0 + wm * 128;
    #pragma unroll
    for (int p = 0; p < 2; ++p) {
      #pragma unroll
      for (int j = 0; j < 4; ++j) {
        const float bn = bias[nb0 + j * 16 + l15];
        #pragma unroll
        for (int il = 0; il < 4; ++il)
          #pragma unroll
          for (int r = 0; r < 4; ++r)
            ep[(il*16 + quad*4 + r) * 64 + j*16 + l15] =
                f2bf(fmaxf(acc[p*4 + il][j][r] + bn, 0.f));
      }
      #pragma unroll
      for (int it = 0; it < 8; ++it) {
        const int tl = it * 8 + (lane >> 3), c = lane & 7;
        uint4 v = *(const uint4*)(ep + tl * 64 + c * 8);
        *(uint4*)(Cb + (size_t)(rbase + p*64 + tl) * E_ + nb0 + c * 8) = v;
      }
    }
    return;
  }

  // MODE 0: z = 0 (k), 1 (q): row-major (b,h,t,d). z = 2 (v): transposed (b,h,d,t).
  const int z = nb0 >> 10, hh = (nb0 >> 6) & 15;
  const int rows0 = row0 + wm * 128;
  const int bb = rows0 >> 8, tb = rows0 & 255;
  if (z < 2) {
    u16* out = (z == 0 ? Cb : Cb2) + ((size_t)(bb * H_ + hh) * T_ + tb) * HD_;
    #pragma unroll
    for (int p = 0; p < 2; ++p) {
      #pragma unroll
      for (int il = 0; il < 4; ++il)
        #pragma unroll
        for (int j = 0; j < 4; ++j)
          #pragma unroll
          for (int r = 0; r < 4; ++r)
            ep[(il*16 + quad*4 + r) * 64 + j*16 + l15] = f2bf(acc[p*4 + il][j][r]);
      #pragma unroll
      for (int it = 0; it < 8; ++it) {
        const int tl = it * 8 + (lane >> 3), c = lane & 7;
        uint4 v = *(const uint4*)(ep + tl * 64 + c * 8);
        *(uint4*)(out + (size_t)(p*64 + tl) * HD_ + c * 8) = v;
      }
    }
  } else {
    // v^T: write [d][t'-64-slab], chunk-swizzled: phys = (tl>>3) ^ (d&7)
    u16* out = (u16*)Cf + ((size_t)(bb * H_ + hh) * HD_) * T_;
    #pragma unroll
    for (int p = 0; p < 2; ++p) {
      #pragma unroll
      for (int il = 0; il < 4; ++il)
        #pragma unroll
        for (int j = 0; j < 4; ++j)
          #pragma unroll
          for (int r = 0; r < 4; ++r) {
            const int tl = il*16 + quad*4 + r, dd = j*16 + l15;
            const int cs = (tl >> 3) ^ (dd & 7);
            ep[dd * 64 + cs * 8 + (tl & 7)] = f2bf(acc[p*4 + il][j][r]);
          }
      #pragma unroll
      for (int it = 0; it < 8; ++it) {
        const int dd = it * 8 + (lane >> 3), c = lane & 7;
        const int cs = c ^ (dd & 7);
        uint4 v = *(const uint4*)(ep + dd * 64 + cs * 8);
        *(uint4*)(out + (size_t)dd * T_ + tb + p*64 + c * 8) = v;
      }
    }
  }
}

// ---------- MFMA flash attention, swapped-QK^T (unchanged from round 8) ----------
__global__ __launch_bounds__(256, 2) void fattn_kernel(
    const u16* __restrict__ kk_, const u16* __restrict__ qq_,
    const u16* __restrict__ vt_, u16* __restrict__ out)
{
  __shared__ __align__(16) u16 Pb[4][64 * 72];  // per-wave private (final transpose)
  const int tid = threadIdx.x, lane = tid & 63, wv = tid >> 6;
  const int bh = blockIdx.x * 4 + wv;
  const int tblk = 3 - (int)blockIdx.y;
  const int l15 = lane & 15, quad = lane >> 4;
  const u16* kb  = kk_ + (size_t)bh * (T_ * HD_);
  const u16* qb  = qq_ + (size_t)bh * (T_ * HD_);
  const u16* vtb = vt_ + (size_t)bh * (HD_ * T_);
  u16* Pw = Pb[wv];

  bf16x8 kf[4][2];
  #pragma unroll
  for (int i = 0; i < 4; ++i)
    #pragma unroll
    for (int c = 0; c < 2; ++c)
      kf[i][c] = *(const bf16x8*)(kb + (size_t)(tblk*64 + i*16 + l15) * HD_ + c*32 + quad*8);

  bf16x8 qf[4][2];
  #pragma unroll
  for (int j = 0; j < 4; ++j)
    #pragma unroll
    for (int c = 0; c < 2; ++c)
      qf[j][c] = *(const bf16x8*)(qb + (size_t)(j*16 + l15) * HD_ + c*32 + quad*8);

  f32x4 accT[4][4];            // [jd][i]: O^T[d=jd*16+quad*4+r][t=i*16+l15]
  float mrow[4], lrow[4];
  #pragma unroll
  for (int i = 0; i < 4; ++i) {
    #pragma unroll
    for (int jd = 0; jd < 4; ++jd) accT[jd][i] = (f32x4){0.f, 0.f, 0.f, 0.f};
    mrow[i] = -1e30f; lrow[i] = 0.f;
  }

  for (int sb = 0; sb <= tblk; ++sb) {
    f32x4 ST[4][4];
    __builtin_amdgcn_s_setprio(1);
    #pragma unroll
    for (int j = 0; j < 4; ++j)
      #pragma unroll
      for (int i = 0; i < 4; ++i) {
        f32x4 t0 = __builtin_amdgcn_mfma_f32_16x16x32_bf16(qf[j][0], kf[i][0],
                       (f32x4){0.f,0.f,0.f,0.f}, 0, 0, 0);
        ST[j][i] = __builtin_amdgcn_mfma_f32_16x16x32_bf16(qf[j][1], kf[i][1], t0, 0, 0, 0);
      }
    __builtin_amdgcn_s_setprio(0);
    if (sb < tblk) {
      #pragma unroll
      for (int j = 0; j < 4; ++j)
        #pragma unroll
        for (int c = 0; c < 2; ++c)
          qf[j][c] = *(const bf16x8*)(qb + (size_t)((sb+1)*64 + j*16 + l15) * HD_ + c*32 + quad*8);
    }
#ifdef HAVE_MFMA16_1K
    bf16x4 vv[4][4];
    #pragma unroll
    for (int j = 0; j < 4; ++j)
      #pragma unroll
      for (int jd = 0; jd < 4; ++jd)
        vv[j][jd] = *(const bf16x4*)(vtb + (size_t)(jd*16 + l15) * T_ + sb*64 + j*16 + quad*4);
#else
    bf16x8 vf[4][2];
    #pragma unroll
    for (int jd = 0; jd < 4; ++jd)
      #pragma unroll
      for (int c = 0; c < 2; ++c)
        vf[jd][c] = *(const bf16x8*)(vtb + (size_t)(jd*16 + l15) * T_ + sb*64 + c*32 + quad*8);
#endif
    if (sb == tblk) {
      #pragma unroll
      for (int j = 0; j < 4; ++j)
        #pragma unroll
        for (int i = 0; i < 4; ++i)
          #pragma unroll
          for (int r = 0; r < 4; ++r)
            if (j*16 + quad*4 + r > i*16 + l15) ST[j][i][r] = -1e30f;
    }
    #pragma unroll
    for (int i = 0; i < 4; ++i) {
      float mx = ST[0][i][0];
      #pragma unroll
      for (int j = 0; j < 4; ++j)
        #pragma unroll
        for (int r = 0; r < 4; ++r) mx = fmaxf(mx, ST[j][i][r]);
      mx = fmaxf(mx, __shfl_xor(mx, 16));
      mx = fmaxf(mx, __shfl_xor(mx, 32));
      float mn = fmaxf(mrow[i], mx);
      float al = __expf(mrow[i] - mn);
      mrow[i] = mn;
      float sm = 0.f;
      #pragma unroll
      for (int j = 0; j < 4; ++j)
        #pragma unroll
        for (int r = 0; r < 4; ++r) {
          float p = __expf(ST[j][i][r] - mn);
          ST[j][i][r] = p;
          sm += p;
        }
      sm += __shfl_xor(sm, 16);
      sm += __shfl_xor(sm, 32);
      lrow[i] = lrow[i] * al + sm;
      #pragma unroll
      for (int jd = 0; jd < 4; ++jd) accT[jd][i] = accT[jd][i] * al;
    }
#ifdef HAVE_MFMA16_1K
    #pragma unroll
    for (int j = 0; j < 4; ++j) {
      bf16x4 pfj[4];
      #pragma unroll
      for (int i = 0; i < 4; ++i)
        pfj[i] = (bf16x4){(short)f2bf_trunc(ST[j][i][0]), (short)f2bf_trunc(ST[j][i][1]),
                          (short)f2bf_trunc(ST[j][i][2]), (short)f2bf_trunc(ST[j][i][3])};
      __builtin_amdgcn_s_setprio(1);
      #pragma unroll
      for (int jd = 0; jd < 4; ++jd)
        #pragma unroll
        for (int i = 0; i < 4; ++i)
          accT[jd][i] = __builtin_amdgcn_mfma_f32_16x16x16bf16_1k(
              vv[j][jd], pfj[i], accT[jd][i], 0, 0, 0);
      __builtin_amdgcn_s_setprio(0);
    }
#else
    #pragma unroll
    for (int j = 0; j < 4; ++j)
      #pragma unroll
      for (int i = 0; i < 4; ++i)
        #pragma unroll
        for (int r = 0; r < 4; ++r)
          Pw[(i*16 + l15) * 72 + j*16 + quad*4 + r] = f2bf_trunc(ST[j][i][r]);
    bf16x8 pfB[4][2];
    #pragma unroll
    for (int i = 0; i < 4; ++i)
      #pragma unroll
      for (int c = 0; c < 2; ++c)
        pfB[i][c] = *(const bf16x8*)(Pw + (i*16 + l15) * 72 + c*32 + quad*8);
    __builtin_amdgcn_s_setprio(1);
    #pragma unroll
    for (int jd = 0; jd < 4; ++jd)
      #pragma unroll
      for (int i = 0; i < 4; ++i) {
        f32x4 t0 = __builtin_amdgcn_mfma_f32_16x16x32_bf16(vf[jd][0], pfB[i][0], accT[jd][i], 0, 0, 0);
        accT[jd][i] = __builtin_amdgcn_mfma_f32_16x16x32_bf16(vf[jd][1], pfB[i][1], t0, 0, 0, 0);
      }
    __builtin_amdgcn_s_setprio(0);
#endif
  }

  #pragma unroll
  for (int i = 0; i < 4; ++i) {
    float inv = 1.0f / lrow[i];
    #pragma unroll
    for (int jd = 0; jd < 4; ++jd)
      #pragma unroll
      for (int r = 0; r < 4; ++r)
        Pw[(i*16 + l15) * 72 + jd*16 + quad*4 + r] = f2bf(accT[jd][i][r] * inv);
  }
  {
    const int b = bh >> 4, h = bh & 15;
    const uint4* pr = (const uint4*)(Pw + lane * 72);
    uint4* og = (uint4*)(out + ((size_t)(b * T_ + tblk*64 + lane)) * E_ + h * HD_);
    #pragma unroll
    for (int k = 0; k < 8; ++k) og[k] = pr[k];
  }
}

// ---------- launch ----------
extern "C" void kernel_launch(void* const* d_in, const int* in_sizes, int n_in,
                              void* d_out, int out_size, void* d_ws, size_t ws_size,
                              hipStream_t stream) {
  const float* x     = (const float*)d_in[0];
  const float* ln1g  = (const float*)d_in[1];
  const float* ln1b  = (const float*)d_in[2];
  const float* wk    = (const float*)d_in[3];
  const float* wq    = (const float*)d_in[4];
  const float* wv    = (const float*)d_in[5];
  const float* wproj = (const float*)d_in[6];
  const float* bproj = (const float*)d_in[7];
  const float* ln2g  = (const float*)d_in[8];
  const float* ln2b  = (const float*)d_in[9];
  const float* w1    = (const float*)d_in[10];
  const float* b1    = (const float*)d_in[11];
  const float* w2    = (const float*)d_in[12];
  const float* b2    = (const float*)d_in[13];
  float* outp = (float*)d_out;

  // ws (112 MB <= proven 128 MB):
  //  [0,6M) WqkvF | [6,8M) WprojF | [8,10M) W1F | [10,12M) W2F   (fragment-major)
  //  [16,48M) hb bf16 (LN1 out -> attn out)
  //  [48,80M) k bf16 (bhtd) -> h2 bf16 | [80,112M) q bf16 (bhtd) -> ff1 bf16
  // d_out (64MB): v^T bf16 (b,h,d,t) [0,32M) -> x1 fp32 (full) -> out (in-place)
  char* ws = (char*)d_ws;
  const size_t MB = 1024 * 1024;
  u16* wqkvT  = (u16*)(ws);
  u16* wprojT = (u16*)(ws + 6 * MB);
  u16* w1T    = (u16*)(ws + 8 * MB);
  u16* w2T    = (u16*)(ws + 10 * MB);
  u16* hb     = (u16*)(ws + 16 * MB);
  u16* kbuf   = (u16*)(ws + 48 * MB);
  u16* qbuf   = (u16*)(ws + 80 * MB);
  u16* vtbuf  = (u16*)d_out;                   // v^T (b,h,d,t) bf16

  convq_kernel<<<dim3(48, 16), 256, 0, stream>>>(wk, wq, wv, wqkvT);
  convt3_kernel<<<dim3(16, 16, 3), 256, 0, stream>>>(wproj, w1, w2, wprojT, w1T, w2T);

  // 1) hb = LN1(x) bf16
  ln_bf16_kernel<<<NTOK/4, 256, 0, stream>>>(x, ln1g, ln1b, hb);
  // 2) k,q bf16 (bhtd; q pre-scaled by 1/8) + v^T bf16 (bhdt, d_out) = hb @ WqkvF
  mgemm_kernel<0><<<768, 512, 0, stream>>>(
      hb, wqkvT, nullptr, nullptr, (float*)vtbuf, kbuf, qbuf);
  // 3) MFMA flash attention (swapped, reg-resident P) -> bf16 row-major into hb
  fattn_kernel<<<dim3(B_*H_/4, 4), 256, 0, stream>>>(kbuf, qbuf, vtbuf, hb);
  // 4) x1 = x + attn @ wproj + bproj -> fp32 d_out (v^T dead)
  mgemm_kernel<1><<<256, 512, 0, stream>>>(
      hb, wprojT, bproj, x, outp, nullptr, nullptr);
  // 5) h2 = LN2(x1) bf16 (over dead k)
  ln_bf16_kernel<<<NTOK/4, 256, 0, stream>>>(outp, ln2g, ln2b, kbuf);
  // 6) ff1 = relu(h2 @ w1 + b1) bf16 (over dead q)
  mgemm_kernel<2><<<256, 512, 0, stream>>>(
      kbuf, w1T, b1, nullptr, nullptr, qbuf, nullptr);
  // 7) out = x1 + ff1 @ w2 + b2, in-place over d_out
  mgemm_kernel<3><<<256, 512, 0, stream>>>(
      qbuf, w2T, b2, nullptr, outp, nullptr, nullptr);
}